// Round 5
// baseline (146.554 us; speedup 1.0000x reference)
//
#include <hip/hip_runtime.h>
#include <math.h>

#define BATCH 32
#define MROWS 120
#define JDIM  64
#define DIM   512
#define NROW  (BATCH * MROWS)   // 3840
#define MPAD  128

#define NCHUNK 15               // n-chunks per batch
#define NC_LEN 8                // n-rows per chunk (15*8 = 120)
#define K2BLK  (BATCH * NCHUNK) // 480

#define LOGIT_SCALE 14.285714285714283f

typedef float f4 __attribute__((ext_vector_type(4)));

// ---------------------------------------------------------------------------
// K1: skel_f[b,m,:] = normalize( sum_j skeleton[b,m,j,:] )   (1/64 cancels)
// one block per (b,m); 256 threads; linear nontemporal float4 stream.
// ---------------------------------------------------------------------------
__global__ __launch_bounds__(256) void k_skel_mean_norm(
    const float* __restrict__ skel_in, float* __restrict__ skel_f)
{
    const int row = blockIdx.x;          // b*120 + m
    const int t   = threadIdx.x;         // 0..255
    const int wid = t >> 6, lane = t & 63;

    const f4* __restrict__ src =
        (const f4*)(skel_in + (size_t)row * (JDIM * DIM));

    f4 acc = (f4){0.f, 0.f, 0.f, 0.f};
    #pragma unroll 8
    for (int it = 0; it < 32; ++it) {
        f4 v = __builtin_nontemporal_load(&src[it * 256 + t]);
        acc += v;
    }

    // combine even-j half (t<128) with odd-j half (t+128), same d4 slot
    __shared__ f4 part[128];
    if (t >= 128) part[t - 128] = acc;
    __syncthreads();

    float ss = 0.f;
    if (t < 128) {
        acc += part[t];
        ss = acc.x * acc.x + acc.y * acc.y + acc.z * acc.z + acc.w * acc.w;
    }

    #pragma unroll
    for (int o = 32; o > 0; o >>= 1) ss += __shfl_xor(ss, o, 64);
    __shared__ float wsum[4];
    if (lane == 0) wsum[wid] = ss;
    __syncthreads();
    const float inv = 1.0f / sqrtf(wsum[0] + wsum[1] + wsum[2] + wsum[3]);

    if (t < 128) {
        f4* __restrict__ dst = (f4*)(skel_f + (size_t)row * DIM);
        dst[t] = acc * inv;
    }
}

// ---------------------------------------------------------------------------
// Kt: textT[b][d][m] = text[b][m][d]  (raw), scale[b*120+m] = SCALE/||text||
// one block per (b,m); 128 threads (thread owns d = 4t..4t+3)
// ---------------------------------------------------------------------------
__global__ __launch_bounds__(128) void k_text_prep(
    const float* __restrict__ text, float* __restrict__ textT,
    float* __restrict__ scale)
{
    const int row = blockIdx.x;          // b*120 + m
    const int b   = row / MROWS;
    const int m   = row - b * MROWS;
    const int t   = threadIdx.x;         // 0..127
    const int wid = t >> 6, lane = t & 63;

    f4 v = ((const f4*)(text + (size_t)row * DIM))[t];
    float ss = v.x * v.x + v.y * v.y + v.z * v.z + v.w * v.w;
    #pragma unroll
    for (int o = 32; o > 0; o >>= 1) ss += __shfl_xor(ss, o, 64);

    __shared__ float red[2];
    if (lane == 0) red[wid] = ss;
    __syncthreads();

    // scattered transpose store: d = 4t+i, stride MPAD floats per d
    float* __restrict__ dst = textT + ((size_t)b * DIM + 4 * t) * MPAD + m;
    dst[0 * MPAD] = v.x;
    dst[1 * MPAD] = v.y;
    dst[2 * MPAD] = v.z;
    dst[3 * MPAD] = v.w;

    if (t == 0) scale[row] = LOGIT_SCALE / sqrtf(red[0] + red[1]);
}

// ---------------------------------------------------------------------------
// K2: block = (b, nc); 128 threads; lane t = text row m.
// acc[k] = sum_d text[b][t][d] * skel_f[b][n0+k][d]
//   tv  : coalesced per-lane load from textT
//   skel: wave-uniform -> scalar loads (s_load), no cross-lane reduce at all
// per-lane LSE partial over the 8 local n, diagonal capture.
// ---------------------------------------------------------------------------
__global__ __launch_bounds__(128) void k_logits(
    const float* __restrict__ textT, const float* __restrict__ skel_f,
    const float* __restrict__ scale, float* __restrict__ part_mx,
    float* __restrict__ part_se, float* __restrict__ diag)
{
    const int blk = blockIdx.x;          // b*NCHUNK + nc
    const int b   = blk / NCHUNK;
    const int nc  = blk - b * NCHUNK;
    const int n0  = nc * NC_LEN;
    const int t   = threadIdx.x;         // 0..127 (m; 120..127 idle lanes)

    const float* __restrict__ tT = textT + (size_t)b * DIM * MPAD + t;
    const float* __restrict__ sk = skel_f + ((size_t)b * MROWS + n0) * DIM;

    float acc[NC_LEN];
    #pragma unroll
    for (int k = 0; k < NC_LEN; ++k) acc[k] = 0.f;

    #pragma unroll 8
    for (int d = 0; d < DIM; ++d) {
        const float tv = tT[(size_t)d * MPAD];
        #pragma unroll
        for (int k = 0; k < NC_LEN; ++k)
            acc[k] = fmaf(tv, sk[k * DIM + d], acc[k]);
    }

    if (t < MROWS) {
        const float sc = scale[b * MROWS + t];

        float lg[NC_LEN];
        float mx = -INFINITY;
        #pragma unroll
        for (int k = 0; k < NC_LEN; ++k) {
            lg[k] = sc * acc[k];
            mx = fmaxf(mx, lg[k]);
        }
        float se = 0.f;
        #pragma unroll
        for (int k = 0; k < NC_LEN; ++k) se += expf(lg[k] - mx);

        part_mx[(size_t)blk * MPAD + t] = mx;
        part_se[(size_t)blk * MPAD + t] = se;

        if ((t >> 3) == nc)              // this chunk holds n == t
            diag[b * MPAD + t] = lg[t - n0];
    }
}

// ---------------------------------------------------------------------------
// K3: per (b,m) combine the 15 LSE partials; per-batch partial sum of
//     (diag - lse).  block = b; 128 threads (t = m).
// ---------------------------------------------------------------------------
__global__ __launch_bounds__(128) void k_combine(
    const float* __restrict__ part_mx, const float* __restrict__ part_se,
    const float* __restrict__ diag, float* __restrict__ bpart)
{
    const int b = blockIdx.x;
    const int t = threadIdx.x;
    const int wid = t >> 6, lane = t & 63;

    float val = 0.f;
    if (t < MROWS) {
        float mx = -INFINITY;
        #pragma unroll
        for (int nc = 0; nc < NCHUNK; ++nc)
            mx = fmaxf(mx, part_mx[(size_t)(b * NCHUNK + nc) * MPAD + t]);
        float se = 0.f;
        #pragma unroll
        for (int nc = 0; nc < NCHUNK; ++nc) {
            const size_t i = (size_t)(b * NCHUNK + nc) * MPAD + t;
            se += part_se[i] * expf(part_mx[i] - mx);
        }
        const float lse = mx + logf(se);
        val = diag[b * MPAD + t] - lse;
    }

    #pragma unroll
    for (int o = 32; o > 0; o >>= 1) val += __shfl_xor(val, o, 64);
    __shared__ float red[2];
    if (lane == 0) red[wid] = val;
    __syncthreads();
    if (t == 0) bpart[b] = red[0] + red[1];
}

// ---------------------------------------------------------------------------
// K4: out = -sum(bpart) / NROW
// ---------------------------------------------------------------------------
__global__ __launch_bounds__(64) void k_final(
    const float* __restrict__ bpart, float* __restrict__ out)
{
    const int t = threadIdx.x;
    float s = (t < BATCH) ? bpart[t] : 0.f;
    #pragma unroll
    for (int o = 32; o > 0; o >>= 1) s += __shfl_xor(s, o, 64);
    if (t == 0) out[0] = -s * (1.0f / (float)NROW);
}

extern "C" void kernel_launch(void* const* d_in, const int* in_sizes, int n_in,
                              void* d_out, int out_size, void* d_ws, size_t ws_size,
                              hipStream_t stream)
{
    const float* skel_in = (const float*)d_in[0];   // (32,120,64,512) f32
    const float* text    = (const float*)d_in[1];   // (32,120,512)    f32
    float* out = (float*)d_out;

    float* skel_f  = (float*)d_ws;                        // 3840*512      = 1.97M f32
    float* textT   = skel_f  + (size_t)NROW * DIM;        // 32*512*128    = 2.10M f32
    float* scale   = textT   + (size_t)BATCH * DIM * MPAD;// 4096
    float* part_mx = scale   + 4096;                      // 480*128
    float* part_se = part_mx + (size_t)K2BLK * MPAD;      // 480*128
    float* diag    = part_se + (size_t)K2BLK * MPAD;      // 32*128
    float* bpart   = diag    + (size_t)BATCH * MPAD;      // 32

    k_skel_mean_norm<<<NROW,  256, 0, stream>>>(skel_in, skel_f);
    k_text_prep     <<<NROW,  128, 0, stream>>>(text, textT, scale);
    k_logits        <<<K2BLK, 128, 0, stream>>>(textT, skel_f, scale,
                                                part_mx, part_se, diag);
    k_combine       <<<BATCH, 128, 0, stream>>>(part_mx, part_se, diag, bpart);
    k_final         <<<1,      64, 0, stream>>>(bpart, out);
}